// Round 16
// baseline (91.872 us; speedup 1.0000x reference)
//
#include <hip/hip_runtime.h>
#include <math.h>

#define DD 4096
#define EE 64
#define NTOK 8192
#define BM 32            // tokens per block (full-K, fused topk)
#define KC 128           // K-chunk per pipeline step
#define NCH (DD / KC)    // 32 steps
#define TAU 4e-3f        // near-tie flag threshold (split err ~1e-5 RMS)

typedef __attribute__((ext_vector_type(8))) short short8;
typedef __attribute__((ext_vector_type(4))) float f32x4;

__device__ __forceinline__ unsigned short f2bf(float f) {   // RNE bf16
    unsigned int u = __float_as_uint(f);
    return (unsigned short)((u + 0x7FFFu + ((u >> 16) & 1u)) >> 16);
}
__device__ __forceinline__ float bf2f(unsigned short h) {
    return __uint_as_float((unsigned int)h << 16);
}

// ---------------------------------------------------------------------------
// prep: W -> bf16 hi/lo split (Wh, Wl); zero the flag counter.
// ---------------------------------------------------------------------------
__global__ void moirai_prep(const float* __restrict__ W,
                            unsigned short* __restrict__ Wh,
                            unsigned short* __restrict__ Wl,
                            int* __restrict__ count) {
    int i = blockIdx.x * 256 + threadIdx.x;
    if (i == 0) *count = 0;
    if (i < EE * DD) {
        float w = W[i];
        unsigned short h = f2bf(w);
        Wh[i] = h;
        Wl[i] = f2bf(w - bf2f(h));
    }
}

// ---------------------------------------------------------------------------
// fused gemm+topk: grid = 256 (1 block/CU), 512 thr (8 waves). Block owns 32
// tokens, FULL K (no K-split, no partials). Wave wv = (mf=wv>>2, nf=wv&3):
// one 16x16 tile, 3-term split-bf16 (merged accL), 12 MFMA per KC=128 step.
// Staging (all global_load_lds, 6 instr/wave/step):
//   x (2): r13's proven swizzle k^4*(r&7), layout [4h][32r][32k'] f32.
//   W (4): r15's proven source-permute q^((e>>1)&3), [4h][4eg][16e][4q][8] bf16
//          per array; wave wv stages array wv>>2, h-chunk wv&3.
// Loop (T3/T4): waitcnt vmcnt(12) -> s_barrier -> compute -> s_barrier ->
// stage(c+3). vmcnt never 0 until tail.
// Epilogue: logits -> lg LDS (aliases dead buffer 0), ballot top-3 per token
// (lowest-index tie-break = jax), flag near-ties, softmax, write.
// ---------------------------------------------------------------------------
__global__ __launch_bounds__(512, 2) void moirai_gemm(
        const float* __restrict__ x,
        const unsigned short* __restrict__ Wh,
        const unsigned short* __restrict__ Wl,
        const float* __restrict__ bias,
        float* __restrict__ out,
        int* __restrict__ count, int* __restrict__ list) {
    __shared__ __align__(16) float          xs3[3][BM * KC];   // 48 KB
    __shared__ __align__(16) unsigned short whs3[3][EE * KC];  // 48 KB
    __shared__ __align__(16) unsigned short wls3[3][EE * KC];  // 48 KB

    const int t    = threadIdx.x;
    const int lane = t & 63;
    const int wv   = t >> 6;          // 0..7
    const int mf   = wv >> 2;         // m-frag 0..1
    const int nf   = wv & 3;          // n-frag 0..3
    const int m0   = blockIdx.x * BM;

    const int fr = lane & 15;         // fragment row (token / expert)
    const int fg = lane >> 4;         // k-group (8 elems)

    f32x4 accH = {0.f, 0.f, 0.f, 0.f};
    f32x4 accL = {0.f, 0.f, 0.f, 0.f};

    // stage one KC=128 chunk into buffer p: 6 global_load_lds per wave.
    auto stage = [&](int p, int c) {
        const int kb = c * KC;
        // x: global instr g = wv*2+i in [0,16): h = g>>2, seg = g&3
#pragma unroll
        for (int i = 0; i < 2; i++) {
            const int g   = wv * 2 + i;
            const int h   = g >> 2;
            const int seg = g & 3;
            const int r   = seg * 8 + (lane >> 3);
            const int kk  = ((lane & 7) * 4) ^ (4 * (r & 7));
            const float* gp = x + (size_t)(m0 + r) * DD + kb + h * 32 + kk;
            float* lp = &xs3[p][h * 1024 + seg * 256];   // wave-uniform base
            __builtin_amdgcn_global_load_lds(
                (const __attribute__((address_space(1))) void*)gp,
                (__attribute__((address_space(3))) void*)lp, 16, 0, 0);
        }
        // W: wave wv -> array a = wv>>2, h = wv&3, e-groups 0..3
        {
            const int a     = wv >> 2;
            const int h     = wv & 3;
            const int e_loc = lane >> 2;
            const int qs    = (lane & 3) ^ ((e_loc >> 1) & 3);
            const unsigned short* gb = a ? Wl : Wh;
            unsigned short*       lb = a ? wls3[p] : whs3[p];
#pragma unroll
            for (int eg = 0; eg < 4; eg++) {
                const unsigned short* gp =
                    gb + (size_t)(eg * 16 + e_loc) * DD + kb + h * 32 + qs * 8;
                unsigned short* lp = lb + h * 2048 + eg * 512;  // wave-uniform
                __builtin_amdgcn_global_load_lds(
                    (const __attribute__((address_space(1))) void*)gp,
                    (__attribute__((address_space(3))) void*)lp, 16, 0, 0);
            }
        }
    };

    auto compute = [&](int p) {
        const int r   = mf * 16 + fr;
        const int q4  = 4 * (fr & 7);
        const int sfg = fg ^ ((fr >> 1) & 3);
#pragma unroll
        for (int h = 0; h < 4; h++) {
            const float4 a0 = *(const float4*)&xs3[p][h * 1024 + r * 32 + ((fg * 8) ^ q4)];
            const float4 a1 = *(const float4*)&xs3[p][h * 1024 + r * 32 + ((fg * 8 + 4) ^ q4)];
            const float v[8] = {a0.x, a0.y, a0.z, a0.w, a1.x, a1.y, a1.z, a1.w};
            short8 ah, al;
#pragma unroll
            for (int i = 0; i < 8; i++) {
                unsigned short hh = f2bf(v[i]);
                ah[i] = (short)hh;
                al[i] = (short)f2bf(v[i] - bf2f(hh));
            }
            const short8 bh = *(const short8*)&whs3[p][h * 2048 + nf * 512 + fr * 32 + sfg * 8];
            const short8 bl = *(const short8*)&wls3[p][h * 2048 + nf * 512 + fr * 32 + sfg * 8];
            accH = __builtin_amdgcn_mfma_f32_16x16x32_bf16(ah, bh, accH, 0, 0, 0);
            accL = __builtin_amdgcn_mfma_f32_16x16x32_bf16(ah, bl, accL, 0, 0, 0);
            accL = __builtin_amdgcn_mfma_f32_16x16x32_bf16(al, bh, accL, 0, 0, 0);
        }
    };

    stage(0, 0);
    stage(1, 1);
    stage(2, 2);                      // 18 DMA outstanding per wave

    for (int c = 0; c < NCH; c++) {
        const int p   = c % 3;
        const int rem = NCH - 1 - c;
        if (rem >= 2)      { asm volatile("s_waitcnt vmcnt(12)" ::: "memory"); }
        else if (rem == 1) { asm volatile("s_waitcnt vmcnt(6)"  ::: "memory"); }
        else               { asm volatile("s_waitcnt vmcnt(0)"  ::: "memory"); }
        __builtin_amdgcn_sched_barrier(0);
        __builtin_amdgcn_s_barrier();   // group c resident for all waves
        __builtin_amdgcn_sched_barrier(0);

        compute(p);

        __builtin_amdgcn_sched_barrier(0);
        __builtin_amdgcn_s_barrier();   // all waves done reading buffer p
        __builtin_amdgcn_sched_barrier(0);
        if (c + 3 < NCH) stage(p, c + 3);
    }

    // ---- fused topk ----
    // logits -> lg (aliases buffer 0: last read at step 30, provably dead)
    float* lg = (float*)xs3[0];       // [32][68]
#pragma unroll
    for (int j = 0; j < 4; j++) {
        // C/D (verified m89/m91): col = lane&15 -> expert, row = fg*4+j -> tok
        const float v = accH[j] + accL[j];
        lg[(mf * 16 + fg * 4 + j) * 68 + nf * 16 + fr] = v;
    }
    __syncthreads();

    const float blv = bias[lane];
#pragma unroll
    for (int tt = 0; tt < 4; tt++) {
        const int tok = wv * 4 + tt;
        const float v = lg[tok * 68 + lane] + blv;

        float m1 = v;
#pragma unroll
        for (int off = 1; off < 64; off <<= 1) m1 = fmaxf(m1, __shfl_xor(m1, off));
        const unsigned long long b1 = __ballot(v == m1);
        const int i1 = (int)__ffsll(b1) - 1;           // lowest index (jax)

        const float vm2 = (lane == i1) ? -3.4e38f : v;
        float m2 = vm2;
#pragma unroll
        for (int off = 1; off < 64; off <<= 1) m2 = fmaxf(m2, __shfl_xor(m2, off));
        const unsigned long long b2 = __ballot(vm2 == m2 && lane != i1);
        const int i2 = (int)__ffsll(b2) - 1;

        const float vm3 = (lane == i1 || lane == i2) ? -3.4e38f : v;
        float m3 = vm3;
#pragma unroll
        for (int off = 1; off < 64; off <<= 1) m3 = fmaxf(m3, __shfl_xor(m3, off));

        if (lane == 0) {
            const int token = m0 + tok;
            if ((m1 - m2 < TAU) || (m2 - m3 < TAU)) {
                int pos = atomicAdd(count, 1);
                list[pos] = token;
            }
            double ex = exp((double)m2 - (double)m1);  // m1 >= m2 -> stable
            double s  = 1.0 + ex;
            out[token * 2 + 0] = (float)(1.0 / s);
            out[token * 2 + 1] = (float)(ex / s);
            out[NTOK * 2 + token * 2 + 0] = (float)i1;
            out[NTOK * 2 + token * 2 + 1] = (float)i2;
        }
    }
}

// ---------------------------------------------------------------------------
// fix: exact f64 recompute of flagged rows, one block (1024 thr) per row.
// x row staged in LDS; 16 lanes per expert row -> coalesced 64B W reads.
// shfl-tree reduce (deterministic) -> wave 0 f64 top-2 (validated comparator).
// ---------------------------------------------------------------------------
__global__ __launch_bounds__(1024) void moirai_fix(
        const float* __restrict__ x, const float* __restrict__ W,
        const float* __restrict__ bias,
        const int* __restrict__ count, const int* __restrict__ list,
        float* __restrict__ out) {
    __shared__ float  xsr[DD];      // 16 KB
    __shared__ double red[EE];

    const int t = threadIdx.x;
    const int e = t >> 4;           // expert 0..63
    const int j = t & 15;           // k-strip within expert
    const int n = *count;

    for (int idx = blockIdx.x; idx < n; idx += gridDim.x) {
        const int token = list[idx];
        *(float4*)&xsr[t * 4] = *(const float4*)(x + (size_t)token * DD + t * 4);
        __syncthreads();

        const float* wr = W + (size_t)e * DD;
        double a0 = 0.0, a1 = 0.0, a2 = 0.0, a3 = 0.0;
#pragma unroll 8
        for (int i = 0; i < DD / 64; i++) {
            const int k = i * 64 + j * 4;
            const float4 xv = *(const float4*)&xsr[k];
            const float4 wv = *(const float4*)(wr + k);
            a0 += (double)xv.x * (double)wv.x;
            a1 += (double)xv.y * (double)wv.y;
            a2 += (double)xv.z * (double)wv.z;
            a3 += (double)xv.w * (double)wv.w;
        }
        double s = (a0 + a1) + (a2 + a3);
#pragma unroll
        for (int off = 1; off < 16; off <<= 1)
            s += __shfl_xor(s, off);          // within 16-lane group
        if (j == 0) red[e] = s;
        __syncthreads();

        if (t < 64) {                          // wave 0: f64 top-2
            double vd = red[t] + (double)bias[t];
            double e1 = vd, e2 = -1.0e300;
            int    f1 = t,  f2 = 127;
#pragma unroll
            for (int off = 1; off < 64; off <<= 1) {
                double u1 = __shfl_xor(e1, off);
                double u2 = __shfl_xor(e2, off);
                int    j1 = __shfl_xor(f1, off);
                int    j2 = __shfl_xor(f2, off);
                bool u1_beats_e1 = (u1 > e1) || (u1 == e1 && j1 < f1);
                if (u1_beats_e1) {
                    bool e1_beats_u2 = (e1 > u2) || (e1 == u2 && f1 < j2);
                    if (e1_beats_u2) { e2 = e1; f2 = f1; }
                    else             { e2 = u2; f2 = j2; }
                    e1 = u1; f1 = j1;
                } else {
                    bool u1_beats_e2 = (u1 > e2) || (u1 == e2 && j1 < f2);
                    if (u1_beats_e2) { e2 = u1; f2 = j1; }
                }
            }
            if (t == 0) {
                double ex = exp(e2 - e1);
                double sm = 1.0 + ex;
                out[token * 2 + 0] = (float)(1.0 / sm);
                out[token * 2 + 1] = (float)(ex / sm);
                out[NTOK * 2 + token * 2 + 0] = (float)f1;
                out[NTOK * 2 + token * 2 + 1] = (float)f2;
            }
        }
        __syncthreads();   // LDS reuse guard
    }
}

// ---------------------------------------------------------------------------
extern "C" void kernel_launch(void* const* d_in, const int* in_sizes, int n_in,
                              void* d_out, int out_size, void* d_ws, size_t ws_size,
                              hipStream_t stream) {
    const float* x = (const float*)d_in[0];
    const float* W = (const float*)d_in[1];
    const float* b = (const float*)d_in[2];
    float* out = (float*)d_out;

    // ws layout: [count|list : 64 KB][Wh 512 KB][Wl 512 KB]
    const size_t HDR = 65536;
    const size_t WSZ = (size_t)EE * DD * 2;
    int*            count = (int*)d_ws;
    int*            list  = (int*)d_ws + 1;
    unsigned short* Wh    = (unsigned short*)((char*)d_ws + HDR);
    unsigned short* Wl    = (unsigned short*)((char*)d_ws + HDR + WSZ);

    moirai_prep<<<(EE * DD + 255) / 256, 256, 0, stream>>>(W, Wh, Wl, count);
    moirai_gemm<<<NTOK / BM, 512, 0, stream>>>(x, Wh, Wl, b, out, count, list);
    moirai_fix<<<256, 1024, 0, stream>>>(x, W, b, count, list, out);
}